// Round 12
// baseline (304.663 us; speedup 1.0000x reference)
//
#include <hip/hip_runtime.h>

#define NNODES 100000
#define NEDGES 1600000
#define DIM 128
#define BN_EPS 1e-5f
#define NBUCK 1024              // coarse buckets, dst>>7 -> 782 used
#define NB_USED ((NNODES + 127) / 128)   // 782
#define HISTB 256               // histogram blocks == k_bpair blocks (1:1 ranges)
#define EPB (NEDGES / HISTB)    // 6250 edges per block

typedef unsigned int uint;
typedef unsigned short ushort_t;
using bhalf8  = __attribute__((ext_vector_type(8))) short;
using u16x8   = __attribute__((ext_vector_type(8))) unsigned short;
using f32x4_t = __attribute__((ext_vector_type(4))) float;

__device__ __forceinline__ float bf2f(uint u16) {
    return __uint_as_float(u16 << 16);
}
__device__ __forceinline__ ushort_t f2bf(float f) {
    uint u = __float_as_uint(f);
    u += 0x7FFFu + ((u >> 16) & 1u);
    return (ushort_t)(u >> 16);
}
__device__ __forceinline__ uint pack2_bf16rn(float a, float b) {
    uint ua = __float_as_uint(a); ua += 0x7FFFu + ((ua >> 16) & 1u);
    uint ub = __float_as_uint(b); ub += 0x7FFFu + ((ub >> 16) & 1u);
    return __builtin_amdgcn_perm(ub, ua, 0x07060302u);  // {a.hi16, b.hi16}
}

// ---- edge access helper: flag=1 -> int64 layout, flag=0 -> int32 -----------
__device__ __forceinline__ int edge_src(const int* ei, int fl, int e) {
    return fl ? ei[2 * e] : ei[e];
}
__device__ __forceinline__ int edge_dst(const int* ei, int fl, int e) {
    return fl ? ei[2 * (NEDGES + e)] : ei[NEDGES + e];
}

// ---------------- merged prep ------------------------------------------------
// bid 0..HISTB-1: private dst-histograms (FIRST: latency hides under xconv)
// bid HISTB..+3: weight bf16 transpose | bid HISTB+4: stats zero + flag
// rest: x -> bf16 streaming (uniform fast tail)
__global__ __launch_bounds__(256) void k_prep(const float* __restrict__ X,
                                              const int* __restrict__ ei,
                                              const float* __restrict__ w0,
                                              const float* __restrict__ w1,
                                              const float* __restrict__ w2,
                                              const float* __restrict__ w3,
                                              float* __restrict__ stats,
                                              int* __restrict__ flag,
                                              int* __restrict__ parts,
                                              ushort_t* __restrict__ wbuf,
                                              ushort_t* __restrict__ Xb) {
    __shared__ int h[NBUCK];
    int bid = blockIdx.x;
    int t = threadIdx.x;
    if (bid < HISTB) {
        // private histogram of dst over NBUCK coarse buckets
        for (int i = t; i < NBUCK; i += 256) h[i] = 0;
        __syncthreads();
        int orr = 0;                             // self-detect edge dtype
#pragma unroll
        for (int i = 1; i < 64; i += 2) orr |= ei[i];
        int fl = (orr == 0) ? 1 : 0;
        int e0 = bid * EPB, e1 = e0 + EPB;
        int e = e0 + t;
        for (; e + 768 < e1; e += 1024) {       // 4 independent loads/iter (ILP)
            int d0 = edge_dst(ei, fl, e);
            int d1 = edge_dst(ei, fl, e + 256);
            int d2 = edge_dst(ei, fl, e + 512);
            int d3 = edge_dst(ei, fl, e + 768);
            atomicAdd(&h[d0 >> 7], 1);
            atomicAdd(&h[d1 >> 7], 1);
            atomicAdd(&h[d2 >> 7], 1);
            atomicAdd(&h[d3 >> 7], 1);
        }
        for (; e < e1; e += 256)
            atomicAdd(&h[edge_dst(ei, fl, e) >> 7], 1);
        __syncthreads();
        for (int i = t; i < NBUCK; i += 256) parts[bid * NBUCK + i] = h[i];
    } else if (bid < HISTB + 4) {
        // weight prep: fp32 [k][n] -> bf16-RN transposed [n][k]
        int wi = bid - HISTB;
        const float* w = (wi == 0) ? w0 : (wi == 1) ? w1 : (wi == 2) ? w2 : w3;
        ushort_t* oh = wbuf + (size_t)wi * 16384;
        for (int i = t; i < 16384; i += 256) {
            int k = i >> 7, n = i & 127;
            oh[n * 128 + k] = f2bf(w[i]);
        }
    } else if (bid == HISTB + 4) {
        stats[t] = 0.0f;
        if (t == 0) {
            int orr = 0;
            for (int i = 1; i < 128; i += 2) orr |= ei[i];
            *flag = (orr == 0) ? 1 : 0;
        }
    } else {
        // x (fp32) -> xb (bf16 RN), 8 elems/thread
        size_t i = ((size_t)(bid - HISTB - 5) * 256 + t) * 8;
        float4 a = *(const float4*)(X + i);
        float4 b = *(const float4*)(X + i + 4);
        union { uint4 q; u16x8 v; } o;
        o.q.x = pack2_bf16rn(a.x, a.y);
        o.q.y = pack2_bf16rn(a.z, a.w);
        o.q.z = pack2_bf16rn(b.x, b.y);
        o.q.w = pack2_bf16rn(b.z, b.w);
        *(u16x8*)(Xb + i) = o.v;
    }
}

// ---------------- single-pass pair scatter -----------------------------------
// Prologue: stream parts (1 MB, L2-resident) to derive this block's exact
// per-bucket write base = bstart[b] + sum_{k'<k} parts[k'][b]. Then ONE edge
// pass scatters packed (src<<7|dst&127) directly to final bucket positions.
// Block 0 publishes bstart for k_bsort.
__global__ __launch_bounds__(256) void k_bpair(const int* __restrict__ ei,
                                               const int* __restrict__ flag,
                                               const int* __restrict__ parts,
                                               int* __restrict__ bstart,
                                               int* __restrict__ pairs) {
    __shared__ int cur[NBUCK];
    __shared__ int wtot[4];
    int k = blockIdx.x, t = threadIdx.x;
    int lane = t & 63, w = t >> 6;
    int4 pre = make_int4(0, 0, 0, 0);   // sum_{k'<k} parts[k'][4 buckets]
    int4 tot = make_int4(0, 0, 0, 0);   // sum over all 256
    for (int kk = 0; kk < HISTB; ++kk) {
        int4 v = ((const int4*)(parts + kk * NBUCK))[t];
        if (kk < k) { pre.x += v.x; pre.y += v.y; pre.z += v.z; pre.w += v.w; }
        tot.x += v.x; tot.y += v.y; tot.z += v.z; tot.w += v.w;
    }
    // block-wide exscan of tot over 1024 buckets -> global bucket starts
    int s = tot.x + tot.y + tot.z + tot.w;
    int sc = s;
#pragma unroll
    for (int d = 1; d < 64; d <<= 1) {
        int n = __shfl_up(sc, d, 64);
        if (lane >= d) sc += n;
    }
    if (lane == 63) wtot[w] = sc;
    __syncthreads();
    int woff = 0;
    for (int i = 0; i < w; ++i) woff += wtot[i];
    int excl = woff + sc - s;
    int b0 = excl, b1 = b0 + tot.x, b2 = b1 + tot.y, b3 = b2 + tot.z;
    cur[t * 4]     = b0 + pre.x;
    cur[t * 4 + 1] = b1 + pre.y;
    cur[t * 4 + 2] = b2 + pre.z;
    cur[t * 4 + 3] = b3 + pre.w;
    if (k == 0) {
        bstart[t * 4]     = b0;
        bstart[t * 4 + 1] = b1;
        bstart[t * 4 + 2] = b2;
        bstart[t * 4 + 3] = b3;
        if (t == 255) bstart[NBUCK] = b3 + tot.w;
    }
    __syncthreads();
    // single edge pass: direct scatter
    int fl = *flag;
    int e0 = k * EPB, e1 = e0 + EPB;
    for (int e = e0 + t; e < e1; e += 256) {
        int src = edge_src(ei, fl, e);
        int d = edge_dst(ei, fl, e);
        int b = d >> 7;
        int pos = atomicAdd(&cur[b], 1);
        pairs[pos] = (src << 7) | (d & 127);
    }
}

// ---------------- per-bucket sort by row -> ssrc + row ends -----------------
__global__ __launch_bounds__(256) void k_bsort(const int* __restrict__ pairs,
                                               const int* __restrict__ bstart,
                                               int* __restrict__ C,
                                               int* __restrict__ ssrc) {
    __shared__ int cnt[128];
    __shared__ int off[128];
    int b = blockIdx.x;
    int t = threadIdx.x, lane = t & 63, w = t >> 6;
    int s = bstart[b], e = bstart[b + 1];
    if (t < 128) cnt[t] = 0;
    __syncthreads();
    for (int i = s + t; i < e; i += 256)
        atomicAdd(&cnt[pairs[i] & 127], 1);
    __syncthreads();
    if (w == 0) {   // wave-scan 128 bins
        int c0 = cnt[lane], c1 = cnt[64 + lane];
        int s0 = c0, s1 = c1;
#pragma unroll
        for (int d = 1; d < 64; d <<= 1) {
            int n0 = __shfl_up(s0, d, 64);
            int n1 = __shfl_up(s1, d, 64);
            if (lane >= d) { s0 += n0; s1 += n1; }
        }
        int tot0 = __shfl(s0, 63, 64);
        off[lane]      = s0 - c0;
        off[64 + lane] = tot0 + s1 - c1;
    }
    __syncthreads();
    if (t < 128) {
        int row = b * 128 + t;
        if (row < NNODES) C[row] = s + off[t] + cnt[t];
    }
    __syncthreads();
    for (int i = s + t; i < e; i += 256) {
        int p = pairs[i];
        int pos = atomicAdd(&off[p & 127], 1);
        ssrc[s + pos] = p >> 7;
    }
}

// ---------------- gather-aggregate (bf16 neighbors) -> bf16 z ---------------
// BN=true: compute scale/shift in-block from raw stats (k_bn folded in).
template <bool BN, bool SELF_F32>
__global__ __launch_bounds__(256) void k_agg(const ushort_t* __restrict__ Xb,
                                             const float* __restrict__ Xf,
                                             ushort_t* __restrict__ Zb,
                                             const int* __restrict__ ends,
                                             const int* __restrict__ ssrc,
                                             const float* __restrict__ stats,
                                             const float* __restrict__ gamma,
                                             const float* __restrict__ beta) {
    __shared__ float scs[128], shs[128];
    int t = threadIdx.x;
    if (BN) {
        if (t < 128) {
            float s  = stats[t];
            float sq = stats[128 + t];
            float mean = s / (float)NNODES;
            float var  = sq / (float)NNODES - mean * mean;
            float sc = gamma[t] * rsqrtf(var + BN_EPS);
            scs[t] = sc;
            shs[t] = beta[t] - mean * sc;
        }
        __syncthreads();
    }
    int g = t >> 4;          // 0..15 row in block
    int l = t & 15;
    int row = blockIdx.x * 16 + g;
    int c8 = l * 8;
    int start = (row == 0) ? 0 : ends[row - 1];
    int end = ends[row];

    float acc[8];
    if (SELF_F32) {
        float4 a0 = *(const float4*)(Xf + (size_t)row * DIM + c8);
        float4 a1 = *(const float4*)(Xf + (size_t)row * DIM + c8 + 4);
        acc[0] = a0.x; acc[1] = a0.y; acc[2] = a0.z; acc[3] = a0.w;
        acc[4] = a1.x; acc[5] = a1.y; acc[6] = a1.z; acc[7] = a1.w;
    } else {
        union { u16x8 v; uint u[4]; } sv;
        sv.v = *(const u16x8*)(Xb + (size_t)row * DIM + c8);
#pragma unroll
        for (int i = 0; i < 4; ++i) {
            acc[2 * i]     = bf2f(sv.u[i] & 0xffffu);
            acc[2 * i + 1] = __uint_as_float(sv.u[i] & 0xffff0000u);
        }
    }

    int e = start;
    for (; e + 7 < end; e += 8) {
        union { u16x8 v; uint u[4]; } nv[8];
#pragma unroll
        for (int i = 0; i < 8; ++i) {
            int s0 = ssrc[e + i];
            nv[i].v = *(const u16x8*)(Xb + (size_t)s0 * DIM + c8);
        }
#pragma unroll
        for (int i = 0; i < 8; ++i) {
#pragma unroll
            for (int j = 0; j < 4; ++j) {
                acc[2 * j]     += bf2f(nv[i].u[j] & 0xffffu);
                acc[2 * j + 1] += __uint_as_float(nv[i].u[j] & 0xffff0000u);
            }
        }
    }
    for (; e < end; ++e) {
        int s0 = ssrc[e];
        union { u16x8 v; uint u[4]; } nv;
        nv.v = *(const u16x8*)(Xb + (size_t)s0 * DIM + c8);
#pragma unroll
        for (int j = 0; j < 4; ++j) {
            acc[2 * j]     += bf2f(nv.u[j] & 0xffffu);
            acc[2 * j + 1] += __uint_as_float(nv.u[j] & 0xffff0000u);
        }
    }

    if (BN) {
        float4 sc0 = *(const float4*)(scs + c8);
        float4 sc1 = *(const float4*)(scs + c8 + 4);
        float4 sh0 = *(const float4*)(shs + c8);
        float4 sh1 = *(const float4*)(shs + c8 + 4);
        float cnt = (float)(end - start + 1);
        acc[0] = fmaf(acc[0], sc0.x, cnt * sh0.x);
        acc[1] = fmaf(acc[1], sc0.y, cnt * sh0.y);
        acc[2] = fmaf(acc[2], sc0.z, cnt * sh0.z);
        acc[3] = fmaf(acc[3], sc0.w, cnt * sh0.w);
        acc[4] = fmaf(acc[4], sc1.x, cnt * sh1.x);
        acc[5] = fmaf(acc[5], sc1.y, cnt * sh1.y);
        acc[6] = fmaf(acc[6], sc1.z, cnt * sh1.z);
        acc[7] = fmaf(acc[7], sc1.w, cnt * sh1.w);
    }
    // z -> bf16 (halves write traffic; MLP consumes bf16 directly)
    union { uint4 q; u16x8 v; } o;
    o.q.x = pack2_bf16rn(acc[0], acc[1]);
    o.q.y = pack2_bf16rn(acc[2], acc[3]);
    o.q.z = pack2_bf16rn(acc[4], acc[5]);
    o.q.w = pack2_bf16rn(acc[6], acc[7]);
    *(u16x8*)(Zb + (size_t)row * DIM + c8) = o.v;
}

// ---------------- fused 2-layer MLP, plain bf16 MFMA, LDS weights -----------
// z bf16 from global; mid bf16 in LDS (16 KB). CONV1: 3 blocks/CU.
template <bool CONV1>
__global__ __launch_bounds__(256, CONV1 ? 3 : 2)
void k_mlp(const ushort_t* __restrict__ Z,
           const ushort_t* __restrict__ WAh,
           const ushort_t* __restrict__ WBh,
           const float* __restrict__ Ba,
           const float* __restrict__ Bb,
           float* __restrict__ OutF,
           ushort_t* __restrict__ OutB,
           float* __restrict__ stats) {
    __shared__ ushort_t wsl[16384];             // 32 KB: current layer weights
    __shared__ char hstage[CONV1 ? 16384 : 32768]; // mid bf16 / out staging
    __shared__ float lsum[128], lsq[128];

    int t = threadIdx.x;
    int w = t >> 6, l = t & 63;
    int lr = l & 15;
    int lg = l >> 4;
    int slane = (lr & 7) << 4;
    if (CONV1 && t < 128) { lsum[t] = 0.f; lsq[t] = 0.f; }

    int rowBase = blockIdx.x * 64 + w * 16;
    bool active = rowBase < NNODES;

    // ---- stage Wa: linear global read -> swizzled LDS write ----
#pragma unroll
    for (int i = 0; i < 8; ++i) {
        int c = i * 256 + t;
        uint4 v = ((const uint4*)WAh)[c];
        ((uint4*)wsl)[c ^ ((c >> 4) & 7)] = v;
    }
    // ---- load z rows (bf16, global) ----
    int zrow = active ? (rowBase + lr) : 0;
    const ushort_t* zp = Z + (size_t)zrow * 128 + lg * 8;
    bhalf8 za[4];
#pragma unroll
    for (int ks = 0; ks < 4; ++ks) za[ks] = *(const bhalf8*)(zp + ks * 32);
    f32x4_t acc[8];
#pragma unroll
    for (int nt = 0; nt < 8; ++nt) {
        float b = Ba[nt * 16 + lr];
        acc[nt][0] = b; acc[nt][1] = b; acc[nt][2] = b; acc[nt][3] = b;
    }
    __syncthreads();   // Wa staged

    // ---- layer 1: mid = relu(Z @ Wa + Ba) ----
#pragma unroll
    for (int ks = 0; ks < 4; ++ks) {
#pragma unroll
        for (int nt = 0; nt < 8; ++nt) {
            int waddr = ((nt * 16 + lr) << 8) + ((((ks << 6) + (lg << 4))) ^ slane);
            bhalf8 wh = *(const bhalf8*)((const char*)wsl + waddr);
            acc[nt] = __builtin_amdgcn_mfma_f32_16x16x32_bf16(za[ks], wh, acc[nt], 0, 0, 0);
        }
    }
    // mid (relu, bf16) -> hstage, transposed store, XOR-swizzled
#pragma unroll
    for (int nt = 0; nt < 8; ++nt) {
#pragma unroll
        for (int j = 0; j < 4; ++j) {
            int rl = w * 16 + lg * 4 + j;
            int boff = (rl * 256 + (nt * 16 + lr) * 2) ^ ((rl & 7) << 4);
            *(ushort_t*)(hstage + boff) = f2bf(fmaxf(acc[nt][j], 0.f));
        }
    }
    __syncthreads();   // Wa reads + mid writes complete

    // ---- stage Wb over Wa; read mid A-frags (bf16, no split) ----
#pragma unroll
    for (int i = 0; i < 8; ++i) {
        int c = i * 256 + t;
        uint4 v = ((const uint4*)WBh)[c];
        ((uint4*)wsl)[c ^ ((c >> 4) & 7)] = v;
    }
    {
        int rl = w * 16 + lr;
        int swz = (rl & 7) << 4;
#pragma unroll
        for (int ks = 0; ks < 4; ++ks)
            za[ks] = *(const bhalf8*)(hstage + ((rl * 256 + (ks * 64 + lg * 16)) ^ swz));
    }
#pragma unroll
    for (int nt = 0; nt < 8; ++nt) {
        float b = Bb[nt * 16 + lr];
        acc[nt][0] = b; acc[nt][1] = b; acc[nt][2] = b; acc[nt][3] = b;
    }
    __syncthreads();   // Wb staged, mid reads complete

    // ---- layer 2: out = mid @ Wb + Bb ----
#pragma unroll
    for (int ks = 0; ks < 4; ++ks) {
#pragma unroll
        for (int nt = 0; nt < 8; ++nt) {
            int waddr = ((nt * 16 + lr) << 8) + ((((ks << 6) + (lg << 4))) ^ slane);
            bhalf8 wh = *(const bhalf8*)((const char*)wsl + waddr);
            acc[nt] = __builtin_amdgcn_mfma_f32_16x16x32_bf16(za[ks], wh, acc[nt], 0, 0, 0);
        }
    }

    // ---- epilogue ----
    if (CONV1 && active) {
#pragma unroll
        for (int nt = 0; nt < 8; ++nt) {
            float s = 0.f, q = 0.f;
#pragma unroll
            for (int j = 0; j < 4; ++j) {
                float v = fmaxf(acc[nt][j], 0.f);
                acc[nt][j] = v;
                s += v; q += v * v;
            }
            s += __shfl_xor(s, 16); s += __shfl_xor(s, 32);
            q += __shfl_xor(q, 16); q += __shfl_xor(q, 32);
            if (l < 16) {
                atomicAdd(&lsum[nt * 16 + l], s);
                atomicAdd(&lsq[nt * 16 + l], q);
            }
        }
    }
    __syncthreads();   // everyone done reading mid from hstage
    if (CONV1) {
        // stage out as bf16 (16 KB), transposed+swizzled
#pragma unroll
        for (int nt = 0; nt < 8; ++nt) {
#pragma unroll
            for (int j = 0; j < 4; ++j) {
                int rl = w * 16 + lg * 4 + j;
                int boff = (rl * 256 + (nt * 16 + lr) * 2) ^ ((rl & 7) << 4);
                *(ushort_t*)(hstage + boff) = f2bf(acc[nt][j]);
            }
        }
        __syncthreads();
        if (t < 128) {
            unsafeAtomicAdd(&stats[t], lsum[t]);
            unsafeAtomicAdd(&stats[128 + t], lsq[t]);
        }
        // readback: 4 threads/row, 4x16B each, coalesced bf16 stores
        int r2 = t >> 2;
        int row = blockIdx.x * 64 + r2;
        if (row < NNODES) {
            int sw2 = (r2 & 7) << 4;
#pragma unroll
            for (int u = 0; u < 4; ++u) {
                int uu = (t & 3) * 4 + u;
                uint4 v = *(const uint4*)(hstage + ((r2 * 256 + uu * 16) ^ sw2));
                *(uint4*)(OutB + (size_t)row * 128 + uu * 8) = v;
            }
        }
    } else {
        // stage out as fp32 (32 KB), transposed+swizzled
#pragma unroll
        for (int nt = 0; nt < 8; ++nt) {
#pragma unroll
            for (int j = 0; j < 4; ++j) {
                int rl = w * 16 + lg * 4 + j;
                int boff = (rl * 512 + (nt * 16 + lr) * 4) ^ ((rl & 7) << 4);
                *(float*)(hstage + boff) = acc[nt][j];
            }
        }
        __syncthreads();
        int r2 = t >> 2;
        int row = blockIdx.x * 64 + r2;
        if (row < NNODES) {
            int sw2 = (r2 & 7) << 4;
            int ch0 = (t & 3) * 8;
#pragma unroll
            for (int c = 0; c < 8; ++c) {
                float4 v = *(const float4*)(hstage + ((r2 * 512 + (ch0 + c) * 16) ^ sw2));
                *(float4*)(OutF + (size_t)row * 128 + (ch0 + c) * 4) = v;
            }
        }
    }
}

extern "C" void kernel_launch(void* const* d_in, const int* in_sizes, int n_in,
                              void* d_out, int out_size, void* d_ws, size_t ws_size,
                              hipStream_t stream) {
    const float* x     = (const float*)d_in[0];
    const int*   ei    = (const int*)d_in[1];
    const float* w1a   = (const float*)d_in[2];
    const float* b1a   = (const float*)d_in[3];
    const float* w1b   = (const float*)d_in[4];
    const float* b1b   = (const float*)d_in[5];
    const float* gamma = (const float*)d_in[6];
    const float* beta  = (const float*)d_in[7];
    const float* w2a   = (const float*)d_in[8];
    const float* b2a   = (const float*)d_in[9];
    const float* w2b   = (const float*)d_in[10];
    const float* b2b   = (const float*)d_in[11];
    float* out = (float*)d_out;

    char* ws = (char*)d_ws;
    float*    stats  = (float*)ws;                  // 256 floats
    int*      flag   = (int*)(ws + 1024);
    int*      bstart = (int*)(ws + 8192);           // 1025 ints
    int*      parts  = (int*)(ws + 0x10000);        // 256 x 1024 ints (1 MB)
    int*      C      = (int*)(ws + 0x180000);       // N ints (row ends)
    int*      ssrc   = (int*)(ws + 0x200000);       // E ints (6.4 MB)
    ushort_t* wbuf   = (ushort_t*)(ws + 0x900000);  // 4 x bf16 weights (128 KB)
    // time-disjoint alias at +0xA00000: pairs (bpair->bsort) -> zbuf (agg->mlp)
    int*      pairs  = (int*)(ws + 0xA00000);       // 6.4 MB
    ushort_t* zbuf   = (ushort_t*)(ws + 0xA00000);  // 25.6 MB

    // bf16 scratch lives inside d_out (split pipeline: xb dead after conv1-agg,
    // hrb dead after conv2-agg, final mlp overwrites all of d_out).
    ushort_t* xb  = (ushort_t*)d_out;                        // [0, 25.6 MB)
    ushort_t* hrb = (ushort_t*)d_out + (size_t)NNODES * DIM; // [25.6, 51.2 MB)

    const int aggBlocks  = NNODES / 16;                       // 6250
    const int prepBlocks = HISTB + 5 + NNODES * DIM / (256 * 8); // 6511
    const int mlpBlocks  = (NNODES + 63) / 64;                // 1563

    // ---- prep (histograms FIRST + weights + setup + x->bf16) ----
    k_prep<<<prepBlocks, 256, 0, stream>>>(x, ei, w1a, w1b, w2a, w2b,
                                           stats, flag, parts, wbuf, xb);
    // ---- single-pass scatter (bases derived from parts in-prologue) ----
    k_bpair<<<HISTB, 256, 0, stream>>>(ei, flag, parts, bstart, pairs);
    k_bsort<<<NB_USED, 256, 0, stream>>>(pairs, bstart, C, ssrc);
    // ---- conv1 ----
    k_agg<false, true><<<aggBlocks, 256, 0, stream>>>(xb, x, zbuf, C, ssrc,
                                                      nullptr, nullptr, nullptr);
    k_mlp<true><<<mlpBlocks, 256, 0, stream>>>(
        zbuf, wbuf, wbuf + 16384, b1a, b1b, nullptr, hrb, stats);
    // ---- conv2 (BN finalize folded into k_agg preamble) ----
    k_agg<true, false><<<aggBlocks, 256, 0, stream>>>(hrb, nullptr, zbuf, C, ssrc,
                                                      stats, gamma, beta);
    k_mlp<false><<<mlpBlocks, 256, 0, stream>>>(
        zbuf, wbuf + 32768, wbuf + 49152, b2a, b2b, out, nullptr, nullptr);
}

// Round 13
// 291.685 us; speedup vs baseline: 1.0445x; 1.0445x over previous
//
#include <hip/hip_runtime.h>

#define NNODES 100000
#define NEDGES 1600000
#define DIM 128
#define BN_EPS 1e-5f
#define NBUCK 1024              // coarse buckets, dst>>7 -> 782 used
#define NB_USED ((NNODES + 127) / 128)   // 782
#define HISTB 128               // histogram blocks in k_prep (dispatched FIRST)

typedef unsigned int uint;
typedef unsigned short ushort_t;
using bhalf8  = __attribute__((ext_vector_type(8))) short;
using u16x8   = __attribute__((ext_vector_type(8))) unsigned short;
using f32x4_t = __attribute__((ext_vector_type(4))) float;

__device__ __forceinline__ float bf2f(uint u16) {
    return __uint_as_float(u16 << 16);
}
__device__ __forceinline__ ushort_t f2bf(float f) {
    uint u = __float_as_uint(f);
    u += 0x7FFFu + ((u >> 16) & 1u);
    return (ushort_t)(u >> 16);
}
__device__ __forceinline__ uint pack2_bf16rn(float a, float b) {
    uint ua = __float_as_uint(a); ua += 0x7FFFu + ((ua >> 16) & 1u);
    uint ub = __float_as_uint(b); ub += 0x7FFFu + ((ub >> 16) & 1u);
    return __builtin_amdgcn_perm(ub, ua, 0x07060302u);  // {a.hi16, b.hi16}
}

// ---- edge access helper: flag=1 -> int64 layout, flag=0 -> int32 -----------
__device__ __forceinline__ int edge_src(const int* ei, int fl, int e) {
    return fl ? ei[2 * e] : ei[e];
}
__device__ __forceinline__ int edge_dst(const int* ei, int fl, int e) {
    return fl ? ei[2 * (NEDGES + e)] : ei[NEDGES + e];
}

// ---------------- merged prep ------------------------------------------------
// bid 0..HISTB-1: private dst-histograms (FIRST: latency hides under xconv)
// bid HISTB..+3: weight bf16 transpose | bid HISTB+4: stats zero + flag
// rest: x -> bf16 streaming (uniform fast tail)
__global__ __launch_bounds__(256) void k_prep(const float* __restrict__ X,
                                              const int* __restrict__ ei,
                                              const float* __restrict__ w0,
                                              const float* __restrict__ w1,
                                              const float* __restrict__ w2,
                                              const float* __restrict__ w3,
                                              float* __restrict__ stats,
                                              int* __restrict__ flag,
                                              int* __restrict__ parts,
                                              ushort_t* __restrict__ wbuf,
                                              ushort_t* __restrict__ Xb) {
    __shared__ int h[NBUCK];
    int bid = blockIdx.x;
    int t = threadIdx.x;
    if (bid < HISTB) {
        // private histogram of dst over NBUCK coarse buckets
        for (int i = t; i < NBUCK; i += 256) h[i] = 0;
        __syncthreads();
        int orr = 0;                             // self-detect edge dtype
#pragma unroll
        for (int i = 1; i < 64; i += 2) orr |= ei[i];
        int fl = (orr == 0) ? 1 : 0;
        int e0 = bid * (NEDGES / HISTB), e1 = e0 + NEDGES / HISTB;
        int e = e0 + t;
        for (; e + 768 < e1; e += 1024) {       // 4 independent loads/iter (ILP)
            int d0 = edge_dst(ei, fl, e);
            int d1 = edge_dst(ei, fl, e + 256);
            int d2 = edge_dst(ei, fl, e + 512);
            int d3 = edge_dst(ei, fl, e + 768);
            atomicAdd(&h[d0 >> 7], 1);
            atomicAdd(&h[d1 >> 7], 1);
            atomicAdd(&h[d2 >> 7], 1);
            atomicAdd(&h[d3 >> 7], 1);
        }
        for (; e < e1; e += 256)
            atomicAdd(&h[edge_dst(ei, fl, e) >> 7], 1);
        __syncthreads();
        for (int i = t; i < NBUCK; i += 256) parts[bid * NBUCK + i] = h[i];
    } else if (bid < HISTB + 4) {
        // weight prep: fp32 [k][n] -> bf16-RN transposed [n][k]
        int wi = bid - HISTB;
        const float* w = (wi == 0) ? w0 : (wi == 1) ? w1 : (wi == 2) ? w2 : w3;
        ushort_t* oh = wbuf + (size_t)wi * 16384;
        for (int i = t; i < 16384; i += 256) {
            int k = i >> 7, n = i & 127;
            oh[n * 128 + k] = f2bf(w[i]);
        }
    } else if (bid == HISTB + 4) {
        stats[t] = 0.0f;
        if (t == 0) {
            int orr = 0;
            for (int i = 1; i < 128; i += 2) orr |= ei[i];
            *flag = (orr == 0) ? 1 : 0;
        }
    } else {
        // x (fp32) -> xb (bf16 RN), 8 elems/thread
        size_t i = ((size_t)(bid - HISTB - 5) * 256 + t) * 8;
        float4 a = *(const float4*)(X + i);
        float4 b = *(const float4*)(X + i + 4);
        union { uint4 q; u16x8 v; } o;
        o.q.x = pack2_bf16rn(a.x, a.y);
        o.q.y = pack2_bf16rn(a.z, a.w);
        o.q.z = pack2_bf16rn(b.x, b.y);
        o.q.w = pack2_bf16rn(b.z, b.w);
        *(u16x8*)(Xb + i) = o.v;
    }
}

// ---------------- reduce partials + exscan of 1024 bucket counts ------------
__global__ __launch_bounds__(256) void k_bscan(const int* __restrict__ parts,
                                               int* __restrict__ bstart,
                                               int* __restrict__ bcur) {
    __shared__ int wtot[4];
    int t = threadIdx.x, lane = t & 63, w = t >> 6;
    int4 v = make_int4(0, 0, 0, 0);
    for (int b = 0; b < HISTB; ++b) {
        int4 p = ((const int4*)(parts + b * NBUCK))[t];
        v.x += p.x; v.y += p.y; v.z += p.z; v.w += p.w;
    }
    int s = v.x + v.y + v.z + v.w;
    int sc = s;
#pragma unroll
    for (int d = 1; d < 64; d <<= 1) {
        int n = __shfl_up(sc, d, 64);
        if (lane >= d) sc += n;
    }
    if (lane == 63) wtot[w] = sc;
    __syncthreads();
    int woff = 0;
    for (int i = 0; i < w; ++i) woff += wtot[i];
    int excl = woff + sc - s;
    int o0 = excl, o1 = o0 + v.x, o2 = o1 + v.y, o3 = o2 + v.z;
    bstart[t * 4]     = o0;  bcur[t * 4]     = o0;
    bstart[t * 4 + 1] = o1;  bcur[t * 4 + 1] = o1;
    bstart[t * 4 + 2] = o2;  bcur[t * 4 + 2] = o2;
    bstart[t * 4 + 3] = o3;  bcur[t * 4 + 3] = o3;
    if (t == 255) bstart[NBUCK] = o3 + v.w;
}

// ---------------- scatter packed (src<<7|dst&127) into coarse buckets -------
__global__ __launch_bounds__(256) void k_bpair(const int* __restrict__ ei,
                                               const int* __restrict__ flag,
                                               int* __restrict__ bcur,
                                               int* __restrict__ pairs) {
    __shared__ int h[NBUCK];
    __shared__ int base[NBUCK];
    int t = threadIdx.x;
    for (int i = t; i < NBUCK; i += 256) h[i] = 0;
    __syncthreads();
    int fl = *flag;
    int per = (NEDGES + gridDim.x - 1) / gridDim.x;
    int e0 = blockIdx.x * per;
    int e1 = min(e0 + per, NEDGES);
    for (int e = e0 + t; e < e1; e += 256)
        atomicAdd(&h[edge_dst(ei, fl, e) >> 7], 1);
    __syncthreads();
    for (int i = t; i < NBUCK; i += 256) {
        int c = h[i];
        base[i] = c ? atomicAdd(&bcur[i], c) : 0;
    }
    __syncthreads();
    for (int i = t; i < NBUCK; i += 256) h[i] = 0;
    __syncthreads();
    for (int e = e0 + t; e < e1; e += 256) {
        int s = edge_src(ei, fl, e);
        int d = edge_dst(ei, fl, e);
        int b = d >> 7;
        int pos = atomicAdd(&h[b], 1);
        pairs[base[b] + pos] = (s << 7) | (d & 127);
    }
}

// ---------------- per-bucket sort by row -> ssrc + row ends -----------------
// Register-stages the first 2048 pairs (single global read of the bucket;
// tail beyond 2048 is streamed twice — rare).
__global__ __launch_bounds__(256) void k_bsort(const int* __restrict__ pairs,
                                               const int* __restrict__ bstart,
                                               int* __restrict__ C,
                                               int* __restrict__ ssrc) {
    __shared__ int cnt[128];
    __shared__ int off[128];
    int b = blockIdx.x;
    int t = threadIdx.x, lane = t & 63, w = t >> 6;
    int s = bstart[b], e = bstart[b + 1];
    if (t < 128) cnt[t] = 0;
    __syncthreads();
    int p[8];
#pragma unroll
    for (int j = 0; j < 8; ++j) {
        int idx = s + t + j * 256;
        p[j] = (idx < e) ? pairs[idx] : -1;     // packed values are >= 0
    }
#pragma unroll
    for (int j = 0; j < 8; ++j)
        if (p[j] >= 0) atomicAdd(&cnt[p[j] & 127], 1);
    for (int i = s + 2048 + t; i < e; i += 256)
        atomicAdd(&cnt[pairs[i] & 127], 1);
    __syncthreads();
    if (w == 0) {   // wave-scan 128 bins
        int c0 = cnt[lane], c1 = cnt[64 + lane];
        int s0 = c0, s1 = c1;
#pragma unroll
        for (int d = 1; d < 64; d <<= 1) {
            int n0 = __shfl_up(s0, d, 64);
            int n1 = __shfl_up(s1, d, 64);
            if (lane >= d) { s0 += n0; s1 += n1; }
        }
        int tot0 = __shfl(s0, 63, 64);
        off[lane]      = s0 - c0;
        off[64 + lane] = tot0 + s1 - c1;
    }
    __syncthreads();
    if (t < 128) {
        int row = b * 128 + t;
        if (row < NNODES) C[row] = s + off[t] + cnt[t];
    }
    __syncthreads();
#pragma unroll
    for (int j = 0; j < 8; ++j) {
        if (p[j] >= 0) {
            int pos = atomicAdd(&off[p[j] & 127], 1);
            ssrc[s + pos] = p[j] >> 7;
        }
    }
    for (int i = s + 2048 + t; i < e; i += 256) {
        int pp = pairs[i];
        int pos = atomicAdd(&off[pp & 127], 1);
        ssrc[s + pos] = pp >> 7;
    }
}

// ---------------- gather-aggregate (bf16 neighbors) -> bf16 z ---------------
// BN=true: compute scale/shift in-block from raw stats (k_bn folded in).
template <bool BN, bool SELF_F32>
__global__ __launch_bounds__(256) void k_agg(const ushort_t* __restrict__ Xb,
                                             const float* __restrict__ Xf,
                                             ushort_t* __restrict__ Zb,
                                             const int* __restrict__ ends,
                                             const int* __restrict__ ssrc,
                                             const float* __restrict__ stats,
                                             const float* __restrict__ gamma,
                                             const float* __restrict__ beta) {
    __shared__ float scs[128], shs[128];
    int t = threadIdx.x;
    if (BN) {
        if (t < 128) {
            float s  = stats[t];
            float sq = stats[128 + t];
            float mean = s / (float)NNODES;
            float var  = sq / (float)NNODES - mean * mean;
            float sc = gamma[t] * rsqrtf(var + BN_EPS);
            scs[t] = sc;
            shs[t] = beta[t] - mean * sc;
        }
        __syncthreads();
    }
    int g = t >> 4;          // 0..15 row in block
    int l = t & 15;
    int row = blockIdx.x * 16 + g;
    int c8 = l * 8;
    int start = (row == 0) ? 0 : ends[row - 1];
    int end = ends[row];

    float acc[8];
    if (SELF_F32) {
        float4 a0 = *(const float4*)(Xf + (size_t)row * DIM + c8);
        float4 a1 = *(const float4*)(Xf + (size_t)row * DIM + c8 + 4);
        acc[0] = a0.x; acc[1] = a0.y; acc[2] = a0.z; acc[3] = a0.w;
        acc[4] = a1.x; acc[5] = a1.y; acc[6] = a1.z; acc[7] = a1.w;
    } else {
        union { u16x8 v; uint u[4]; } sv;
        sv.v = *(const u16x8*)(Xb + (size_t)row * DIM + c8);
#pragma unroll
        for (int i = 0; i < 4; ++i) {
            acc[2 * i]     = bf2f(sv.u[i] & 0xffffu);
            acc[2 * i + 1] = __uint_as_float(sv.u[i] & 0xffff0000u);
        }
    }

    int e = start;
    for (; e + 7 < end; e += 8) {
        union { u16x8 v; uint u[4]; } nv[8];
#pragma unroll
        for (int i = 0; i < 8; ++i) {
            int s0 = ssrc[e + i];
            nv[i].v = *(const u16x8*)(Xb + (size_t)s0 * DIM + c8);
        }
#pragma unroll
        for (int i = 0; i < 8; ++i) {
#pragma unroll
            for (int j = 0; j < 4; ++j) {
                acc[2 * j]     += bf2f(nv[i].u[j] & 0xffffu);
                acc[2 * j + 1] += __uint_as_float(nv[i].u[j] & 0xffff0000u);
            }
        }
    }
    for (; e < end; ++e) {
        int s0 = ssrc[e];
        union { u16x8 v; uint u[4]; } nv;
        nv.v = *(const u16x8*)(Xb + (size_t)s0 * DIM + c8);
#pragma unroll
        for (int j = 0; j < 4; ++j) {
            acc[2 * j]     += bf2f(nv.u[j] & 0xffffu);
            acc[2 * j + 1] += __uint_as_float(nv.u[j] & 0xffff0000u);
        }
    }

    if (BN) {
        float4 sc0 = *(const float4*)(scs + c8);
        float4 sc1 = *(const float4*)(scs + c8 + 4);
        float4 sh0 = *(const float4*)(shs + c8);
        float4 sh1 = *(const float4*)(shs + c8 + 4);
        float cnt = (float)(end - start + 1);
        acc[0] = fmaf(acc[0], sc0.x, cnt * sh0.x);
        acc[1] = fmaf(acc[1], sc0.y, cnt * sh0.y);
        acc[2] = fmaf(acc[2], sc0.z, cnt * sh0.z);
        acc[3] = fmaf(acc[3], sc0.w, cnt * sh0.w);
        acc[4] = fmaf(acc[4], sc1.x, cnt * sh1.x);
        acc[5] = fmaf(acc[5], sc1.y, cnt * sh1.y);
        acc[6] = fmaf(acc[6], sc1.z, cnt * sh1.z);
        acc[7] = fmaf(acc[7], sc1.w, cnt * sh1.w);
    }
    // z -> bf16 (halves write traffic; MLP consumes bf16 directly)
    union { uint4 q; u16x8 v; } o;
    o.q.x = pack2_bf16rn(acc[0], acc[1]);
    o.q.y = pack2_bf16rn(acc[2], acc[3]);
    o.q.z = pack2_bf16rn(acc[4], acc[5]);
    o.q.w = pack2_bf16rn(acc[6], acc[7]);
    *(u16x8*)(Zb + (size_t)row * DIM + c8) = o.v;
}

// ---------------- fused 2-layer MLP, plain bf16 MFMA, LDS weights -----------
// z bf16 from global; mid bf16 in LDS (16 KB). CONV1: 3 blocks/CU.
template <bool CONV1>
__global__ __launch_bounds__(256, CONV1 ? 3 : 2)
void k_mlp(const ushort_t* __restrict__ Z,
           const ushort_t* __restrict__ WAh,
           const ushort_t* __restrict__ WBh,
           const float* __restrict__ Ba,
           const float* __restrict__ Bb,
           float* __restrict__ OutF,
           ushort_t* __restrict__ OutB,
           float* __restrict__ stats) {
    __shared__ ushort_t wsl[16384];             // 32 KB: current layer weights
    __shared__ char hstage[CONV1 ? 16384 : 32768]; // mid bf16 / out staging
    __shared__ float lsum[128], lsq[128];

    int t = threadIdx.x;
    int w = t >> 6, l = t & 63;
    int lr = l & 15;
    int lg = l >> 4;
    int slane = (lr & 7) << 4;
    if (CONV1 && t < 128) { lsum[t] = 0.f; lsq[t] = 0.f; }

    int rowBase = blockIdx.x * 64 + w * 16;
    bool active = rowBase < NNODES;

    // ---- stage Wa: linear global read -> swizzled LDS write ----
#pragma unroll
    for (int i = 0; i < 8; ++i) {
        int c = i * 256 + t;
        uint4 v = ((const uint4*)WAh)[c];
        ((uint4*)wsl)[c ^ ((c >> 4) & 7)] = v;
    }
    // ---- load z rows (bf16, global) ----
    int zrow = active ? (rowBase + lr) : 0;
    const ushort_t* zp = Z + (size_t)zrow * 128 + lg * 8;
    bhalf8 za[4];
#pragma unroll
    for (int ks = 0; ks < 4; ++ks) za[ks] = *(const bhalf8*)(zp + ks * 32);
    f32x4_t acc[8];
#pragma unroll
    for (int nt = 0; nt < 8; ++nt) {
        float b = Ba[nt * 16 + lr];
        acc[nt][0] = b; acc[nt][1] = b; acc[nt][2] = b; acc[nt][3] = b;
    }
    __syncthreads();   // Wa staged

    // ---- layer 1: mid = relu(Z @ Wa + Ba) ----
#pragma unroll
    for (int ks = 0; ks < 4; ++ks) {
#pragma unroll
        for (int nt = 0; nt < 8; ++nt) {
            int waddr = ((nt * 16 + lr) << 8) + ((((ks << 6) + (lg << 4))) ^ slane);
            bhalf8 wh = *(const bhalf8*)((const char*)wsl + waddr);
            acc[nt] = __builtin_amdgcn_mfma_f32_16x16x32_bf16(za[ks], wh, acc[nt], 0, 0, 0);
        }
    }
    // mid (relu, bf16) -> hstage, transposed store, XOR-swizzled
#pragma unroll
    for (int nt = 0; nt < 8; ++nt) {
#pragma unroll
        for (int j = 0; j < 4; ++j) {
            int rl = w * 16 + lg * 4 + j;
            int boff = (rl * 256 + (nt * 16 + lr) * 2) ^ ((rl & 7) << 4);
            *(ushort_t*)(hstage + boff) = f2bf(fmaxf(acc[nt][j], 0.f));
        }
    }
    __syncthreads();   // Wa reads + mid writes complete

    // ---- stage Wb over Wa; read mid A-frags (bf16, no split) ----
#pragma unroll
    for (int i = 0; i < 8; ++i) {
        int c = i * 256 + t;
        uint4 v = ((const uint4*)WBh)[c];
        ((uint4*)wsl)[c ^ ((c >> 4) & 7)] = v;
    }
    {
        int rl = w * 16 + lr;
        int swz = (rl & 7) << 4;
#pragma unroll
        for (int ks = 0; ks < 4; ++ks)
            za[ks] = *(const bhalf8*)(hstage + ((rl * 256 + (ks * 64 + lg * 16)) ^ swz));
    }
#pragma unroll
    for (int nt = 0; nt < 8; ++nt) {
        float b = Bb[nt * 16 + lr];
        acc[nt][0] = b; acc[nt][1] = b; acc[nt][2] = b; acc[nt][3] = b;
    }
    __syncthreads();   // Wb staged, mid reads complete

    // ---- layer 2: out = mid @ Wb + Bb ----
#pragma unroll
    for (int ks = 0; ks < 4; ++ks) {
#pragma unroll
        for (int nt = 0; nt < 8; ++nt) {
            int waddr = ((nt * 16 + lr) << 8) + ((((ks << 6) + (lg << 4))) ^ slane);
            bhalf8 wh = *(const bhalf8*)((const char*)wsl + waddr);
            acc[nt] = __builtin_amdgcn_mfma_f32_16x16x32_bf16(za[ks], wh, acc[nt], 0, 0, 0);
        }
    }

    // ---- epilogue ----
    if (CONV1 && active) {
#pragma unroll
        for (int nt = 0; nt < 8; ++nt) {
            float s = 0.f, q = 0.f;
#pragma unroll
            for (int j = 0; j < 4; ++j) {
                float v = fmaxf(acc[nt][j], 0.f);
                acc[nt][j] = v;
                s += v; q += v * v;
            }
            s += __shfl_xor(s, 16); s += __shfl_xor(s, 32);
            q += __shfl_xor(q, 16); q += __shfl_xor(q, 32);
            if (l < 16) {
                atomicAdd(&lsum[nt * 16 + l], s);
                atomicAdd(&lsq[nt * 16 + l], q);
            }
        }
    }
    __syncthreads();   // everyone done reading mid from hstage
    if (CONV1) {
        // stage out as bf16 (16 KB), transposed+swizzled
#pragma unroll
        for (int nt = 0; nt < 8; ++nt) {
#pragma unroll
            for (int j = 0; j < 4; ++j) {
                int rl = w * 16 + lg * 4 + j;
                int boff = (rl * 256 + (nt * 16 + lr) * 2) ^ ((rl & 7) << 4);
                *(ushort_t*)(hstage + boff) = f2bf(acc[nt][j]);
            }
        }
        __syncthreads();
        if (t < 128) {
            unsafeAtomicAdd(&stats[t], lsum[t]);
            unsafeAtomicAdd(&stats[128 + t], lsq[t]);
        }
        // readback: 4 threads/row, 4x16B each, coalesced bf16 stores
        int r2 = t >> 2;
        int row = blockIdx.x * 64 + r2;
        if (row < NNODES) {
            int sw2 = (r2 & 7) << 4;
#pragma unroll
            for (int u = 0; u < 4; ++u) {
                int uu = (t & 3) * 4 + u;
                uint4 v = *(const uint4*)(hstage + ((r2 * 256 + uu * 16) ^ sw2));
                *(uint4*)(OutB + (size_t)row * 128 + uu * 8) = v;
            }
        }
    } else {
        // stage out as fp32 (32 KB), transposed+swizzled
#pragma unroll
        for (int nt = 0; nt < 8; ++nt) {
#pragma unroll
            for (int j = 0; j < 4; ++j) {
                int rl = w * 16 + lg * 4 + j;
                int boff = (rl * 512 + (nt * 16 + lr) * 4) ^ ((rl & 7) << 4);
                *(float*)(hstage + boff) = acc[nt][j];
            }
        }
        __syncthreads();
        int r2 = t >> 2;
        int row = blockIdx.x * 64 + r2;
        if (row < NNODES) {
            int sw2 = (r2 & 7) << 4;
            int ch0 = (t & 3) * 8;
#pragma unroll
            for (int c = 0; c < 8; ++c) {
                float4 v = *(const float4*)(hstage + ((r2 * 512 + (ch0 + c) * 16) ^ sw2));
                *(float4*)(OutF + (size_t)row * 128 + (ch0 + c) * 4) = v;
            }
        }
    }
}

extern "C" void kernel_launch(void* const* d_in, const int* in_sizes, int n_in,
                              void* d_out, int out_size, void* d_ws, size_t ws_size,
                              hipStream_t stream) {
    const float* x     = (const float*)d_in[0];
    const int*   ei    = (const int*)d_in[1];
    const float* w1a   = (const float*)d_in[2];
    const float* b1a   = (const float*)d_in[3];
    const float* w1b   = (const float*)d_in[4];
    const float* b1b   = (const float*)d_in[5];
    const float* gamma = (const float*)d_in[6];
    const float* beta  = (const float*)d_in[7];
    const float* w2a   = (const float*)d_in[8];
    const float* b2a   = (const float*)d_in[9];
    const float* w2b   = (const float*)d_in[10];
    const float* b2b   = (const float*)d_in[11];
    float* out = (float*)d_out;

    char* ws = (char*)d_ws;
    float*    stats  = (float*)ws;                  // 256 floats
    int*      flag   = (int*)(ws + 1024);
    int*      bstart = (int*)(ws + 8192);           // 1025 ints
    int*      bcur   = (int*)(ws + 16384);          // 1024 ints
    int*      C      = (int*)(ws + 404096);         // N ints (row ends)
    int*      ssrc   = (int*)(ws + 804096);         // E ints
    ushort_t* wbuf   = (ushort_t*)(ws + 0x700000);  // 4 x bf16 weights (128 KB)
    // time-disjoint aliasing chain at +0x800000:
    //   parts (k_prep->k_bscan, 512 KB) -> pairs (k_bpair->k_bsort, 6.4 MB)
    //   -> zbuf (k_agg->k_mlp, 25.6 MB)
    int*      parts  = (int*)(ws + 0x800000);
    int*      pairs  = (int*)(ws + 0x800000);
    ushort_t* zbuf   = (ushort_t*)(ws + 0x800000);

    // bf16 scratch lives inside d_out (split pipeline: xb dead after conv1-agg,
    // hrb dead after conv2-agg, final mlp overwrites all of d_out).
    ushort_t* xb  = (ushort_t*)d_out;                        // [0, 25.6 MB)
    ushort_t* hrb = (ushort_t*)d_out + (size_t)NNODES * DIM; // [25.6, 51.2 MB)

    const int aggBlocks  = NNODES / 16;                       // 6250
    const int prepBlocks = HISTB + 5 + NNODES * DIM / (256 * 8); // 6383
    const int mlpBlocks  = (NNODES + 63) / 64;                // 1563

    // ---- prep (histogram FIRST + weights + setup + x->bf16), CSR build ----
    k_prep<<<prepBlocks, 256, 0, stream>>>(x, ei, w1a, w1b, w2a, w2b,
                                           stats, flag, parts, wbuf, xb);
    k_bscan<<<1, 256, 0, stream>>>(parts, bstart, bcur);
    k_bpair<<<256, 256, 0, stream>>>(ei, flag, bcur, pairs);
    k_bsort<<<NB_USED, 256, 0, stream>>>(pairs, bstart, C, ssrc);
    // ---- conv1 ----
    k_agg<false, true><<<aggBlocks, 256, 0, stream>>>(xb, x, zbuf, C, ssrc,
                                                      nullptr, nullptr, nullptr);
    k_mlp<true><<<mlpBlocks, 256, 0, stream>>>(
        zbuf, wbuf, wbuf + 16384, b1a, b1b, nullptr, hrb, stats);
    // ---- conv2 (BN finalize folded into k_agg preamble) ----
    k_agg<true, false><<<aggBlocks, 256, 0, stream>>>(hrb, nullptr, zbuf, C, ssrc,
                                                      stats, gamma, beta);
    k_mlp<false><<<mlpBlocks, 256, 0, stream>>>(
        zbuf, wbuf + 32768, wbuf + 49152, b2a, b2b, out, nullptr, nullptr);
}